// Round 14
// baseline (1754.063 us; speedup 1.0000x reference)
//
#include <hip/hip_runtime.h>
#include <hip/hip_bf16.h>
#include <math.h>

#define B_ 4
#define S_ 512
#define D_ 512
#define F_ 2048
#define L_ 6
#define H_ 8
#define V_ 32000

typedef unsigned short u16;
typedef __attribute__((ext_vector_type(8))) short bhalf8;   // 8 bf16 = 4 VGPRs
typedef __attribute__((ext_vector_type(4))) float f32x4;

__device__ __forceinline__ u16 f2b(float v) {
    unsigned x = __builtin_bit_cast(unsigned, v);
    return (u16)((x + 0x7FFFu + ((x >> 16) & 1u)) >> 16);   // RNE
}

#define GLD16(g, l) __builtin_amdgcn_global_load_lds( \
    (const __attribute__((address_space(1))) void*)(g), \
    (__attribute__((address_space(3))) void*)(l), 16, 0, 0)

__device__ __forceinline__ float redmax16(float v) {
    #pragma unroll
    for (int m = 1; m < 16; m <<= 1) v = fmaxf(v, __shfl_xor(v, m));
    return v;
}
__device__ __forceinline__ float redsum16(float v) {
    #pragma unroll
    for (int m = 1; m < 16; m <<= 1) v += __shfl_xor(v, m);
    return v;
}

// ---------------------------------------------------------------------------
// bf16 MFMA GEMM: C = A*B^T (+bias[col]) (+relu).
// A:[M][K] lda bf16; B:[N][K] ldb bf16 (K-contig). Wave tile WM x WN,
// block = NWR x NWC waves (NW==1 supported: independent self-paced waves).
// 2-phase pipelined K-loop (double-buffered LDS, one barrier per K-step).
// Split-K via gridDim.z. SWZ: XCD-aware 1D-grid decode (16 M-blocks total).
// NT: nontemporal fp32 C stores. VTT (NW=1, BN=64): blocks with bn>=vc0
// write tile transposed via LDS to vtp[(col-vc0)][row] (stride 2048).
// SPLITA: blocks with bn >= acut read A2.
// ---------------------------------------------------------------------------
template<int NWR, int NWC, int WM, int WN, int OUT, int RELU, int MLOOP,
         int SPLITA, int NT, int VTT, int SWZ>
__global__ __launch_bounds__(NWR * NWC * 64)
void mfma_gemm(const u16* __restrict__ A, const u16* __restrict__ A2, int acut,
               const u16* __restrict__ B,
               const float* __restrict__ bias, void* __restrict__ Cv,
               int K, int lda, int ldb, int ldc,
               u16* __restrict__ vtp, int vc0, long zoffC)
{
    constexpr int BM = NWR * WM, BN = NWC * WN;
    constexpr int NW = NWR * NWC;
    constexpr int CH_A = BM / 16, CH_B = BN / 16, CH = CH_A + CH_B;
    constexpr int NI = WM / 16, NJ = WN / 16;
    constexpr int TSTR = BM + 8;

    __shared__ u16 As[2][BM * 32];
    __shared__ u16 Bs[2][BN * 32];
    __shared__ u16 TT[VTT ? 64 * TSTR : 8];

    const int tid = threadIdx.x;
    const int wid = tid >> 6, lane = tid & 63;
    const int wrow = wid / NWC, wcol = wid % NWC;
    long bn, bmbase;
    if (SWZ) {
        long b0 = blockIdx.x;
        long per = (long)gridDim.x >> 3;          // blocks per XCD
        long w = (b0 & 7) * per + (b0 >> 3);
        constexpr int MB = 16 / MLOOP;            // M-blocks per panel
        bn = (w / MB) * BN;
        bmbase = w % MB;
    } else {
        bn = (long)blockIdx.x * BN;
        bmbase = (long)blockIdx.y;
    }
    const int r4 = lane >> 2, c4 = lane & 3;
    const int l15 = lane & 15, l4 = lane >> 4;

    const u16* Ause = (SPLITA && bn >= acut) ? A2 : A;
    const long kz = (long)blockIdx.z * K;         // split-K offset
    Ause += kz;
    B += kz;

    #pragma unroll 1
    for (int mi = 0; mi < MLOOP; ++mi) {
        const long bm = (bmbase * MLOOP + mi) * BM;

        f32x4 acc[NI][NJ];
        #pragma unroll
        for (int i = 0; i < NI; ++i)
            #pragma unroll
            for (int j = 0; j < NJ; ++j)
                acc[i][j] = (f32x4){0.f, 0.f, 0.f, 0.f};

        // stage K-step 0 into buffer 0
        #pragma unroll
        for (int t = 0; t < CH / NW; ++t) {
            int c = wid + t * NW;
            if (c < CH_A) {
                GLD16(Ause + (bm + c * 16 + r4) * (long)lda + c4 * 8,
                      &As[0][c * 512 + lane * 8]);
            } else {
                int cb = c - CH_A;
                GLD16(B + (bn + cb * 16 + r4) * (long)ldb + c4 * 8,
                      &Bs[0][cb * 512 + lane * 8]);
            }
        }

        for (int k0 = 0; k0 < K; k0 += 32) {
            const int cur = (k0 >> 5) & 1;
            __syncthreads();                      // publish buf[cur]
            if (k0 + 32 < K) {                    // prefetch next into buf[cur^1]
                const int kn = k0 + 32;
                #pragma unroll
                for (int t = 0; t < CH / NW; ++t) {
                    int c = wid + t * NW;
                    if (c < CH_A) {
                        GLD16(Ause + (bm + c * 16 + r4) * (long)lda + kn + c4 * 8,
                              &As[cur ^ 1][c * 512 + lane * 8]);
                    } else {
                        int cb = c - CH_A;
                        GLD16(B + (bn + cb * 16 + r4) * (long)ldb + kn + c4 * 8,
                              &Bs[cur ^ 1][cb * 512 + lane * 8]);
                    }
                }
            }
            bhalf8 af[NI], bfr[NJ];
            #pragma unroll
            for (int i = 0; i < NI; ++i)
                af[i] = *(const bhalf8*)&As[cur][(wrow * WM + i * 16 + l15) * 32 + l4 * 8];
            #pragma unroll
            for (int j = 0; j < NJ; ++j)
                bfr[j] = *(const bhalf8*)&Bs[cur][(wcol * WN + j * 16 + l15) * 32 + l4 * 8];
            #pragma unroll
            for (int i = 0; i < NI; ++i)
                #pragma unroll
                for (int j = 0; j < NJ; ++j)
                    acc[i][j] = __builtin_amdgcn_mfma_f32_16x16x32_bf16(af[i], bfr[j], acc[i][j], 0, 0, 0);
        }

        if (VTT && vtp != nullptr && bn >= vc0) {
            // transposed epilogue through LDS (NW=1, BN=64)
            #pragma unroll
            for (int j = 0; j < NJ; ++j) {
                const int cc = wcol * WN + j * 16 + l15;
                const float bv = bias ? bias[bn + cc] : 0.f;
                #pragma unroll
                for (int i = 0; i < NI; ++i) {
                    const int rw = wrow * WM + i * 16 + (l4 << 2);
                    #pragma unroll
                    for (int r = 0; r < 4; ++r)
                        TT[cc * TSTR + rw + r] = f2b(acc[i][j][r] + bv);
                }
            }
            __syncthreads();
            {
                const int cc = tid;                // 64 threads = 64 cols
                const u16* src = &TT[cc * TSTR];
                u16* dst = &vtp[(bn - vc0 + cc) * 2048 + bm];
                #pragma unroll
                for (int p = 0; p < BM / 8; ++p)
                    *(uint4*)(dst + p * 8) = *(const uint4*)(src + p * 8);
            }
            __syncthreads();
            continue;
        }

        float* Cf = (float*)Cv + blockIdx.z * zoffC;
        u16*   Cb = (u16*)Cv  + blockIdx.z * zoffC;
        const int rowb = wrow * WM + (l4 << 2);
        const int colb = wcol * WN + l15;
        #pragma unroll
        for (int j = 0; j < NJ; ++j) {
            const long gc = bn + colb + j * 16;
            const float bv = bias ? bias[gc] : 0.f;
            #pragma unroll
            for (int i = 0; i < NI; ++i) {
                const long gr = bm + rowb + i * 16;
                #pragma unroll
                for (int r = 0; r < 4; ++r) {
                    float v = acc[i][j][r] + bv;
                    if (RELU) v = fmaxf(v, 0.f);
                    if (OUT == 0) {
                        if (NT) __builtin_nontemporal_store(v, &Cf[(gr + r) * (long)ldc + gc]);
                        else    Cf[(gr + r) * (long)ldc + gc] = v;
                    } else {
                        Cb[(gr + r) * (long)ldc + gc] = f2b(v);
                    }
                }
            }
        }
    }
}

// ---------------------------------------------------------------------------
// Fused GEMM + residual + LayerNorm (N=512 full row per block). K=512.
// grid = M/16 blocks, 512 threads = 8 waves; wave w owns cols w*64..w*64+63.
// ---------------------------------------------------------------------------
__global__ __launch_bounds__(512)
void gemm_ln_kernel(const u16* __restrict__ A, const u16* __restrict__ B,
                    const float* __restrict__ bias,
                    float* __restrict__ x, u16* __restrict__ xb,
                    const float* __restrict__ g, const float* __restrict__ bb,
                    int K)
{
    __shared__ u16 As[16 * 32];
    __shared__ u16 Bs[512 * 32];
    __shared__ float red[2][16][8];
    __shared__ float mv[2][16];

    const int tid = threadIdx.x, w = tid >> 6, lane = tid & 63;
    const int l15 = lane & 15, l4 = lane >> 4;
    const int r4 = lane >> 2, c4 = lane & 3;
    const long bm = (long)blockIdx.x * 16;

    f32x4 acc[4];
    #pragma unroll
    for (int j = 0; j < 4; ++j) acc[j] = (f32x4){0.f, 0.f, 0.f, 0.f};

    for (int k0 = 0; k0 < K; k0 += 32) {
        #pragma unroll
        for (int t = 0; t < 5; ++t) {
            int c = w + t * 8;
            if (c < 33) {
                if (c == 0) {
                    GLD16(A + (bm + r4) * (long)K + k0 + c4 * 8, As + lane * 8);
                } else {
                    GLD16(B + ((c - 1) * 16 + r4) * (long)K + k0 + c4 * 8,
                          Bs + (c - 1) * 512 + lane * 8);
                }
            }
        }
        __syncthreads();
        bhalf8 af = *(const bhalf8*)&As[l15 * 32 + l4 * 8];
        #pragma unroll
        for (int j = 0; j < 4; ++j) {
            bhalf8 bf = *(const bhalf8*)&Bs[(w * 64 + j * 16 + l15) * 32 + l4 * 8];
            acc[j] = __builtin_amdgcn_mfma_f32_16x16x32_bf16(af, bf, acc[j], 0, 0, 0);
        }
        __syncthreads();
    }

    // epilogue: residual + row stats + LN
    float vbuf[4][4], s[4] = {0, 0, 0, 0}, s2[4] = {0, 0, 0, 0};
    #pragma unroll
    for (int j = 0; j < 4; ++j) {
        int col = w * 64 + j * 16 + l15;
        float bv = bias[col];
        #pragma unroll
        for (int r = 0; r < 4; ++r) {
            int row = l4 * 4 + r;
            float v = acc[j][r] + bv + x[(bm + row) * 512 + col];
            vbuf[j][r] = v;
            s[r] += v; s2[r] += v * v;
        }
    }
    #pragma unroll
    for (int r = 0; r < 4; ++r) { s[r] = redsum16(s[r]); s2[r] = redsum16(s2[r]); }
    if (l15 == 0) {
        #pragma unroll
        for (int r = 0; r < 4; ++r) {
            red[0][l4 * 4 + r][w] = s[r];
            red[1][l4 * 4 + r][w] = s2[r];
        }
    }
    __syncthreads();
    if (tid < 16) {
        float S = 0.f, S2 = 0.f;
        #pragma unroll
        for (int q = 0; q < 8; ++q) { S += red[0][tid][q]; S2 += red[1][tid][q]; }
        float mean = S * (1.f / 512.f);
        float var = S2 * (1.f / 512.f) - mean * mean;
        mv[0][tid] = mean;
        mv[1][tid] = rsqrtf(var + 1e-6f);
    }
    __syncthreads();
    #pragma unroll
    for (int j = 0; j < 4; ++j) {
        int col = w * 64 + j * 16 + l15;
        float gg = g[col], bbv = bb[col];
        #pragma unroll
        for (int r = 0; r < 4; ++r) {
            int row = l4 * 4 + r;
            float o = (vbuf[j][r] - mv[0][row]) * mv[1][row] * gg + bbv;
            x[(bm + row) * 512 + col] = o;
            xb[(bm + row) * 512 + col] = f2b(o);
        }
    }
}

// ---------------------------------------------------------------------------
// Fused flash attention. One (b,h,64-q-block) per workgroup, 4 waves x 16 q.
// K/V tiles double-buffered; one barrier per tile. s_setprio around MFMA (T5).
// ---------------------------------------------------------------------------
template<int CAUSAL>
__global__ __launch_bounds__(256)
void flash_kernel(const u16* __restrict__ Qp, int ldq,
                  const u16* __restrict__ Kp, int ldk,
                  const u16* __restrict__ Vt,
                  const int* __restrict__ tok,
                  u16* __restrict__ Op)
{
    __shared__ u16 QS[64 * 64];
    __shared__ u16 KS[2][64 * 64];
    __shared__ u16 VS[2][64 * 64];
    __shared__ u16 PS[4 * 16 * 64];
    __shared__ float MK[512];

    const int tid = threadIdx.x, lane = tid & 63, w = tid >> 6;
    const int l15 = lane & 15, l4 = lane >> 4;
    const int qb = blockIdx.x, bh = blockIdx.y;
    const int b = bh >> 3, h = bh & 7;

    const u16* Q = Qp + (long)(b * 512 + qb * 64) * ldq + h * 64;
    const u16* K = Kp + (long)(b * 512) * ldk + h * 64;
    const u16* V = Vt + (long)(h * 64) * 2048 + b * 512;
    u16* O = Op + (long)(b * 512 + qb * 64) * 512 + h * 64;

    {
        int t0 = tok[b * 512 + tid];
        int t1 = tok[b * 512 + 256 + tid];
        MK[tid]       = (t0 == 0) ? -1e9f : 0.f;
        MK[tid + 256] = (t1 == 0) ? -1e9f : 0.f;
    }
    const int r = tid >> 3;
    const int c = (tid & 7) ^ (r & 7);
    {
        GLD16(Q + (long)r * ldq + c * 8,        QS + tid * 8);
        GLD16(Q + (long)(r + 32) * ldq + c * 8, QS + 2048 + tid * 8);
        GLD16(K + (long)r * ldk + c * 8,              KS[0] + tid * 8);
        GLD16(K + (long)(32 + r) * ldk + c * 8,       KS[0] + 2048 + tid * 8);
        GLD16(V + (long)r * 2048 + c * 8,             VS[0] + tid * 8);
        GLD16(V + (long)(r + 32) * 2048 + c * 8,      VS[0] + 2048 + tid * 8);
    }
    __syncthreads();

    bhalf8 qa[2];
    #pragma unroll
    for (int kc = 0; kc < 2; ++kc) {
        int row = w * 16 + l15;
        qa[kc] = *(const bhalf8*)&QS[row * 64 + (((kc * 4 + l4) ^ (row & 7)) << 3)];
    }

    f32x4 oacc[4];
    float mrun[4], lrun[4];
    #pragma unroll
    for (int j = 0; j < 4; ++j) oacc[j] = (f32x4){0.f, 0.f, 0.f, 0.f};
    #pragma unroll
    for (int rr = 0; rr < 4; ++rr) { mrun[rr] = -1e30f; lrun[rr] = 0.f; }

    const int tmax = CAUSAL ? qb : 7;

    for (int t = 0; t <= tmax; ++t) {
        const int cur = t & 1;
        if (t < tmax) {
            const int tn = t + 1;
            GLD16(K + (long)(tn * 64 + r) * ldk + c * 8,        KS[cur ^ 1] + tid * 8);
            GLD16(K + (long)(tn * 64 + 32 + r) * ldk + c * 8,   KS[cur ^ 1] + 2048 + tid * 8);
            GLD16(V + (long)r * 2048 + tn * 64 + c * 8,         VS[cur ^ 1] + tid * 8);
            GLD16(V + (long)(r + 32) * 2048 + tn * 64 + c * 8,  VS[cur ^ 1] + 2048 + tid * 8);
        }
        f32x4 sac[4];
        #pragma unroll
        for (int jj = 0; jj < 4; ++jj) sac[jj] = (f32x4){0.f, 0.f, 0.f, 0.f};
        bhalf8 kf[4][2];
        #pragma unroll
        for (int jj = 0; jj < 4; ++jj)
            #pragma unroll
            for (int kc = 0; kc < 2; ++kc) {
                int row = jj * 16 + l15;
                kf[jj][kc] = *(const bhalf8*)&KS[cur][row * 64 + (((kc * 4 + l4) ^ (row & 7)) << 3)];
            }
        __builtin_amdgcn_s_setprio(1);
        #pragma unroll
        for (int jj = 0; jj < 4; ++jj)
            #pragma unroll
            for (int kc = 0; kc < 2; ++kc)
                sac[jj] = __builtin_amdgcn_mfma_f32_16x16x32_bf16(qa[kc], kf[jj][kc], sac[jj], 0, 0, 0);
        __builtin_amdgcn_s_setprio(0);

        #pragma unroll
        for (int jj = 0; jj < 4; ++jj) {
            float mk = MK[t * 64 + jj * 16 + l15];
            #pragma unroll
            for (int rr = 0; rr < 4; ++rr) {
                float mk2 = mk;
                if (CAUSAL && t == qb) {
                    int col = t * 64 + jj * 16 + l15;
                    int qr = qb * 64 + w * 16 + l4 * 4 + rr;
                    if (col > qr) mk2 = -1e9f;
                }
                sac[jj][rr] = sac[jj][rr] * 0.125f + mk2;
            }
        }
        #pragma unroll
        for (int rr = 0; rr < 4; ++rr) {
            float mx = fmaxf(fmaxf(sac[0][rr], sac[1][rr]), fmaxf(sac[2][rr], sac[3][rr]));
            mx = redmax16(mx);
            float mnew = fmaxf(mrun[rr], mx);
            float alpha = __expf(mrun[rr] - mnew);
            float sum = 0.f;
            int row_p = l4 * 4 + rr;
            #pragma unroll
            for (int jj = 0; jj < 4; ++jj) {
                float pv = __expf(sac[jj][rr] - mnew);
                sum += pv;
                int kv = jj * 16 + l15;
                PS[w * 1024 + row_p * 64 + ((((kv >> 3) ^ (row_p & 7)) << 3) | (kv & 7))] = f2b(pv);
            }
            sum = redsum16(sum);
            lrun[rr] = lrun[rr] * alpha + sum;
            mrun[rr] = mnew;
            #pragma unroll
            for (int jd = 0; jd < 4; ++jd) oacc[jd][rr] *= alpha;
        }
        bhalf8 pa[2], vf[4][2];
        #pragma unroll
        for (int kc = 0; kc < 2; ++kc) {
            int row = l15;
            pa[kc] = *(const bhalf8*)&PS[w * 1024 + row * 64 + (((kc * 4 + l4) ^ (row & 7)) << 3)];
        }
        #pragma unroll
        for (int jd = 0; jd < 4; ++jd)
            #pragma unroll
            for (int kc = 0; kc < 2; ++kc) {
                int row = jd * 16 + l15;
                vf[jd][kc] = *(const bhalf8*)&VS[cur][row * 64 + (((kc * 4 + l4) ^ (row & 7)) << 3)];
            }
        __builtin_amdgcn_s_setprio(1);
        #pragma unroll
        for (int jd = 0; jd < 4; ++jd)
            #pragma unroll
            for (int kc = 0; kc < 2; ++kc)
                oacc[jd] = __builtin_amdgcn_mfma_f32_16x16x32_bf16(pa[kc], vf[jd][kc], oacc[jd], 0, 0, 0);
        __builtin_amdgcn_s_setprio(0);
        __syncthreads();
    }

    #pragma unroll
    for (int rr = 0; rr < 4; ++rr) {
        float inv = 1.f / lrun[rr];
        int row = w * 16 + l4 * 4 + rr;
        #pragma unroll
        for (int jd = 0; jd < 4; ++jd)
            O[(long)row * 512 + jd * 16 + l15] = f2b(oacc[jd][rr] * inv);
    }
}

// ---------------------------------------------------------------------------
// Prep kernels (unchanged)
// ---------------------------------------------------------------------------
__global__ __launch_bounds__(256)
void transpose_many(const float* __restrict__ inA, const float* __restrict__ inB,
                    int zsplit, int R, int C, u16* __restrict__ out)
{
    int z = blockIdx.z;
    const float* in = (z < zsplit) ? inA + (long)z * R * C
                                   : inB + (long)(z - zsplit) * R * C;
    u16* o = out + (long)z * R * C;
    __shared__ float tb[64][65];
    const int tr = blockIdx.y * 64, tc = blockIdx.x * 64;
    const int col = threadIdx.x & 63, r0 = threadIdx.x >> 6;
    #pragma unroll
    for (int p = 0; p < 16; ++p) {
        int row = r0 * 16 + p;
        tb[row][col] = in[(long)(tr + row) * C + tc + col];
    }
    __syncthreads();
    #pragma unroll
    for (int p = 0; p < 16; ++p) {
        int row = r0 * 16 + p;
        o[(long)(tc + row) * R + tr + col] = f2b(tb[col][row]);
    }
}

__global__ __launch_bounds__(256)
void convert_b16(const float4* __restrict__ in, u16* __restrict__ out, long n4)
{
    long i = (long)blockIdx.x * 256 + threadIdx.x;
    if (i >= n4) return;
    float4 v = in[i];
    uint2 p;
    p.x = (unsigned)f2b(v.x) | ((unsigned)f2b(v.y) << 16);
    p.y = (unsigned)f2b(v.z) | ((unsigned)f2b(v.w) << 16);
    *(uint2*)(out + i * 4) = p;
}

// ---------------------------------------------------------------------------
// Embedding (both sequences in one dispatch): x = emb[tok]*scale + pos
// ---------------------------------------------------------------------------
__global__ __launch_bounds__(256)
void embed_kernel(const int* __restrict__ tE, const int* __restrict__ tD,
                  const float* __restrict__ eE, const float* __restrict__ eD,
                  const float* __restrict__ pos,
                  float* __restrict__ xE, float* __restrict__ xD,
                  u16* __restrict__ bE, u16* __restrict__ bD, float scale)
{
    const int z = blockIdx.y;
    const int* tok = z ? tD : tE;
    const float* emb = z ? eD : eE;
    float* x = z ? xD : xE;
    u16* xb = z ? bD : bE;
    int row = blockIdx.x;
    int s = row & (S_ - 1);
    int t = tok[row];
    const float* er = emb + (long)t * D_;
    const float* pr = pos + (long)s * D_;
    float* o = x + (long)row * D_;
    u16*  ob = xb + (long)row * D_;
    int i = threadIdx.x;
    float v0 = er[i]       * scale + pr[i];
    float v1 = er[i + 256] * scale + pr[i + 256];
    o[i] = v0;        o[i + 256] = v1;
    ob[i] = f2b(v0);  ob[i + 256] = f2b(v1);
}

// ---------------------------------------------------------------------------
// x = LayerNorm(x + y0 + y1 + cb) * g + b (fp32 state) + bf16 copy
// ---------------------------------------------------------------------------
__global__ __launch_bounds__(256)
void add_ln_kernel(float* __restrict__ x, const float* __restrict__ y0,
                   const float* __restrict__ y1, const float* __restrict__ cb,
                   u16* __restrict__ xb,
                   const float* __restrict__ g, const float* __restrict__ bb)
{
    long row = blockIdx.x;
    float* xr = x + row * D_;
    u16* xo = xb + row * D_;
    const float* yr0 = y0 + row * D_;
    const float* yr1 = y1 + row * D_;
    int t = threadIdx.x, t2 = t + 256;

    float r0 = xr[t]  + yr0[t]  + yr1[t]  + cb[t];
    float r1 = xr[t2] + yr0[t2] + yr1[t2] + cb[t2];
    float s = r0 + r1;
    float s2 = r0 * r0 + r1 * r1;
    #pragma unroll
    for (int i = 1; i < 64; i <<= 1) {
        s  += __shfl_xor(s, i);
        s2 += __shfl_xor(s2, i);
    }
    __shared__ float rs[4], rs2[4];
    int wid = t >> 6;
    if ((t & 63) == 0) { rs[wid] = s; rs2[wid] = s2; }
    __syncthreads();
    s  = rs[0] + rs[1] + rs[2] + rs[3];
    s2 = rs2[0] + rs2[1] + rs2[2] + rs2[3];

    float mean = s * (1.f / D_);
    float var  = s2 * (1.f / D_) - mean * mean;
    float inv  = rsqrtf(var + 1e-6f);
    float o0 = (r0 - mean) * inv * g[t]  + bb[t];
    float o1 = (r1 - mean) * inv * g[t2] + bb[t2];
    xr[t] = o0;       xr[t2] = o1;
    xo[t] = f2b(o0);  xo[t2] = f2b(o1);
}

// ---------------------------------------------------------------------------
extern "C" void kernel_launch(void* const* d_in, const int* in_sizes, int n_in,
                              void* d_out, int out_size, void* d_ws, size_t ws_size,
                              hipStream_t stream)
{
    const int*   enc_in     = (const int*)  d_in[0];
    const int*   dec_in     = (const int*)  d_in[1];
    const float* e_embed    = (const float*)d_in[2];
    const float* d_embed    = (const float*)d_in[3];
    const float* pos_enc    = (const float*)d_in[4];
    const float* enc_mha_W  = (const float*)d_in[5];
    const float* enc_mha_b  = (const float*)d_in[6];
    const float* enc_ln_g   = (const float*)d_in[7];
    const float* enc_ln_b   = (const float*)d_in[8];
    const float* enc_ffn_W1 = (const float*)d_in[9];
    const float* enc_ffn_b1 = (const float*)d_in[10];
    const float* enc_ffn_W2 = (const float*)d_in[11];
    const float* enc_ffn_b2 = (const float*)d_in[12];
    const float* dec_mha_W  = (const float*)d_in[13];
    const float* dec_mha_b  = (const float*)d_in[14];
    const float* dec_ln_g   = (const float*)d_in[15];
    const float* dec_ln_b   = (const float*)d_in[16];
    const float* dec_ffn_W1 = (const float*)d_in[17];
    const float* dec_ffn_b1 = (const float*)d_in[18];
    const float* dec_ffn_W2 = (const float*)d_in[19];
    const float* dec_ffn_b2 = (const float*)d_in[20];
    float* out = (float*)d_out;

    const int  BS  = B_ * S_;                 // 2048
    const long BSD = (long)BS * D_;
    const long DD  = (long)D_ * D_;
    const long DF  = (long)D_ * F_;

    char* p = (char*)d_ws;
    auto alloc = [&](long bytes) { char* r = p; p += (bytes + 255) & ~255L; return r; };
    float* e    = (float*)alloc(BSD * 4);
    float* dd   = (float*)alloc(BSD * 4);
    float* y    = (float*)alloc(2 * BSD * 4);   // split-K partials y0,y1
    u16*   eb   = (u16*)  alloc(BSD * 2);
    u16*   ddb  = (u16*)  alloc(BSD * 2);
    u16*   qkv  = (u16*)  alloc((long)BS * 1536 * 2);
    u16*   att  = (u16*)  alloc(BSD * 2);
    u16*   vt   = (u16*)  alloc(BSD * 2);
    u16*   ffnh = (u16*)  alloc((long)BS * F_ * 2);
    u16*   wEmb = (u16*)  alloc((long)V_ * D_ * 2);
    u16*   wMha = (u16*)  alloc(72 * DD * 2);
    u16*   wF1  = (u16*)  alloc(12 * DF * 2);
    u16*   wF2  = (u16*)  alloc(12 * DF * 2);

    // ---- weight prep ----
    transpose_many<<<dim3(8, 8, 72), 256, 0, stream>>>(enc_mha_W, dec_mha_W, 24, 512, 512, wMha);
    transpose_many<<<dim3(32, 8, 12), 256, 0, stream>>>(enc_ffn_W1, dec_ffn_W1, 6, 512, 2048, wF1);
    transpose_many<<<dim3(8, 32, 12), 256, 0, stream>>>(enc_ffn_W2, dec_ffn_W2, 6, 2048, 512, wF2);
    convert_b16<<<16000, 256, 0, stream>>>((const float4*)d_embed, wEmb, (long)V_ * D_ / 4);

    const float scale = sqrtf((float)D_);
    embed_kernel<<<dim3(BS, 2), 256, 0, stream>>>(enc_in, dec_in, e_embed, d_embed,
                                                  pos_enc, e, dd, eb, ddb, scale);

    // 1-wave 64x64 skinny GEMM (+V-transpose epilogue), 768 blocks, 3/CU
    #define GEMM_SKV(A, Bp, bias, C) \
        mfma_gemm<1,1,64,64,1,0,1,0,0,1,0><<<dim3(24, 32), 64, 0, stream>>>( \
            A, A, 1 << 30, Bp, bias, C, 512, 512, 512, 1536, vt, 1024, 0)
    // FFN1: 1-wave 64x64, 1024 blocks, 4/CU
    #define GEMM_FFN1(A, Bp, bias, C) \
        mfma_gemm<1,1,64,64,1,1,1,0,0,0,0><<<dim3(32, 32), 64, 0, stream>>>( \
            A, A, 1 << 30, Bp, bias, C, 512, 512, 512, 2048, nullptr, 0, 0)
    // FFN2: split-K=2, 1-wave 64x64, 512 blocks
    #define GEMM_FFN2(A, Bp) \
        mfma_gemm<1,1,64,64,0,0,1,0,0,0,0><<<dim3(8, 32, 2), 64, 0, stream>>>( \
            A, A, 1 << 30, Bp, nullptr, y, 1024, 2048, 2048, 512, nullptr, 0, BSD)

    // ---------------- encoder ----------------
    for (int l = 0; l < L_; ++l) {
        const u16* Wl = wMha + (long)l * 4 * DD;
        const float* bl = enc_mha_b + (long)l * 4 * D_;
        GEMM_SKV(eb, Wl, bl, qkv);
        flash_kernel<0><<<dim3(8, 32), 256, 0, stream>>>(qkv, 1536, qkv + 512, 1536, vt, enc_in, att);
        gemm_ln_kernel<<<128, 512, 0, stream>>>(att, Wl + 3 * DD, bl + 3 * D_,
            e, eb, enc_ln_g + (long)(l * 2) * D_, enc_ln_b + (long)(l * 2) * D_, 512);
        GEMM_FFN1(eb, wF1 + (long)l * DF, enc_ffn_b1 + (long)l * F_, ffnh);
        GEMM_FFN2(ffnh, wF2 + (long)l * DF);
        add_ln_kernel<<<BS, 256, 0, stream>>>(e, y, y + BSD, enc_ffn_b2 + (long)l * D_, eb,
            enc_ln_g + (long)(l * 2 + 1) * D_, enc_ln_b + (long)(l * 2 + 1) * D_);
    }

    // ---------------- decoder ----------------
    for (int l = 0; l < L_; ++l) {
        const u16* Wl = wMha + (long)(24 + l * 8) * DD;
        const float* bl = dec_mha_b + (long)l * 8 * D_;
        // self-attention (causal + dec pad)
        GEMM_SKV(ddb, Wl, bl, qkv);
        flash_kernel<1><<<dim3(8, 32), 256, 0, stream>>>(qkv, 1536, qkv + 512, 1536, vt, dec_in, att);
        gemm_ln_kernel<<<128, 512, 0, stream>>>(att, Wl + 3 * DD, bl + 3 * D_,
            dd, ddb, dec_ln_g + (long)(l * 3) * D_, dec_ln_b + (long)(l * 3) * D_, 512);
        // cross-attention: fused q (from dd) + k,v (from e) projections
        mfma_gemm<1,1,64,64,1,0,1,1,0,1,0><<<dim3(24, 32), 64, 0, stream>>>(
            ddb, eb, 512, Wl + 4 * DD, bl + 4 * D_, qkv,
            512, 512, 512, 1536, vt, 1024, 0);
        flash_kernel<0><<<dim3(8, 32), 256, 0, stream>>>(qkv, 1536, qkv + 512, 1536, vt, enc_in, att);
        gemm_ln_kernel<<<128, 512, 0, stream>>>(att, Wl + 7 * DD, bl + 7 * D_,
            dd, ddb, dec_ln_g + (long)(l * 3 + 1) * D_, dec_ln_b + (long)(l * 3 + 1) * D_, 512);
        // FFN
        GEMM_FFN1(ddb, wF1 + (long)(6 + l) * DF, dec_ffn_b1 + (long)l * F_, ffnh);
        GEMM_FFN2(ffnh, wF2 + (long)(6 + l) * DF);
        add_ln_kernel<<<BS, 256, 0, stream>>>(dd, y, y + BSD, dec_ffn_b2 + (long)l * D_, ddb,
            dec_ln_g + (long)(l * 3 + 2) * D_, dec_ln_b + (long)(l * 3 + 2) * D_);
    }

    // ---------------- logits = dd @ d_embed^T ----------------
    // XCD-swizzled 1D grid, 128x256 tile (2x4 waves), MLOOP=2
    mfma_gemm<2,4,64,64,0,0,2,0,1,0,1><<<dim3(1000), 512, 0, stream>>>(
        ddb, ddb, 1 << 30, wEmb, nullptr, out, 512, 512, 512, 32000, nullptr, 0, 0);
}

// Round 15
// 1636.075 us; speedup vs baseline: 1.0721x; 1.0721x over previous
//
#include <hip/hip_runtime.h>
#include <hip/hip_bf16.h>
#include <math.h>

#define B_ 4
#define S_ 512
#define D_ 512
#define F_ 2048
#define L_ 6
#define H_ 8
#define V_ 32000

typedef unsigned short u16;
typedef __attribute__((ext_vector_type(8))) short bhalf8;   // 8 bf16 = 4 VGPRs
typedef __attribute__((ext_vector_type(4))) float f32x4;

__device__ __forceinline__ u16 f2b(float v) {
    unsigned x = __builtin_bit_cast(unsigned, v);
    return (u16)((x + 0x7FFFu + ((x >> 16) & 1u)) >> 16);   // RNE
}

#define GLD16(g, l) __builtin_amdgcn_global_load_lds( \
    (const __attribute__((address_space(1))) void*)(g), \
    (__attribute__((address_space(3))) void*)(l), 16, 0, 0)

__device__ __forceinline__ float redmax16(float v) {
    #pragma unroll
    for (int m = 1; m < 16; m <<= 1) v = fmaxf(v, __shfl_xor(v, m));
    return v;
}
__device__ __forceinline__ float redsum16(float v) {
    #pragma unroll
    for (int m = 1; m < 16; m <<= 1) v += __shfl_xor(v, m);
    return v;
}

// ---------------------------------------------------------------------------
// bf16 MFMA GEMM: C = A*B^T (+bias[col]) (+relu).
// A:[M][K] lda bf16; B:[N][K] ldb bf16 (K-contig). Wave tile WM x WN,
// block = NWR x NWC waves (NW==1 supported: independent self-paced waves).
// 2-phase pipelined K-loop (double-buffered LDS, one barrier per K-step).
// Split-K via gridDim.z. SWZ: XCD-aware 1D-grid decode (16 M-blocks total).
// NT: nontemporal fp32 C stores. VTT (NW=1, BM=32, BN=64): blocks with
// bn>=vc0 write tile transposed via LDS to vtp[(col-vc0)][row] (stride 2048).
// SPLITA: blocks with bn >= acut read A2.
// ---------------------------------------------------------------------------
template<int NWR, int NWC, int WM, int WN, int OUT, int RELU, int MLOOP,
         int SPLITA, int NT, int VTT, int SWZ>
__global__ __launch_bounds__(NWR * NWC * 64)
void mfma_gemm(const u16* __restrict__ A, const u16* __restrict__ A2, int acut,
               const u16* __restrict__ B,
               const float* __restrict__ bias, void* __restrict__ Cv,
               int K, int lda, int ldb, int ldc,
               u16* __restrict__ vtp, int vc0, long zoffC)
{
    constexpr int BM = NWR * WM, BN = NWC * WN;
    constexpr int NW = NWR * NWC;
    constexpr int CH_A = BM / 16, CH_B = BN / 16, CH = CH_A + CH_B;
    constexpr int NI = WM / 16, NJ = WN / 16;
    constexpr int TSTR = BM + 8;

    __shared__ u16 As[2][BM * 32];
    __shared__ u16 Bs[2][BN * 32];
    __shared__ u16 TT[VTT ? 64 * TSTR : 8];

    const int tid = threadIdx.x;
    const int wid = tid >> 6, lane = tid & 63;
    const int wrow = wid / NWC, wcol = wid % NWC;
    long bn, bmbase;
    if (SWZ) {
        long b0 = blockIdx.x;
        long per = (long)gridDim.x >> 3;          // blocks per XCD
        long w = (b0 & 7) * per + (b0 >> 3);
        constexpr int MB = 16 / MLOOP;            // M-blocks per panel
        bn = (w / MB) * BN;
        bmbase = w % MB;
    } else {
        bn = (long)blockIdx.x * BN;
        bmbase = (long)blockIdx.y;
    }
    const int r4 = lane >> 2, c4 = lane & 3;
    const int l15 = lane & 15, l4 = lane >> 4;

    const u16* Ause = (SPLITA && bn >= acut) ? A2 : A;
    const long kz = (long)blockIdx.z * K;         // split-K offset
    Ause += kz;
    B += kz;

    #pragma unroll 1
    for (int mi = 0; mi < MLOOP; ++mi) {
        const long bm = (bmbase * MLOOP + mi) * BM;

        f32x4 acc[NI][NJ];
        #pragma unroll
        for (int i = 0; i < NI; ++i)
            #pragma unroll
            for (int j = 0; j < NJ; ++j)
                acc[i][j] = (f32x4){0.f, 0.f, 0.f, 0.f};

        // stage K-step 0 into buffer 0
        #pragma unroll
        for (int t = 0; t < CH / NW; ++t) {
            int c = wid + t * NW;
            if (c < CH_A) {
                GLD16(Ause + (bm + c * 16 + r4) * (long)lda + c4 * 8,
                      &As[0][c * 512 + lane * 8]);
            } else {
                int cb = c - CH_A;
                GLD16(B + (bn + cb * 16 + r4) * (long)ldb + c4 * 8,
                      &Bs[0][cb * 512 + lane * 8]);
            }
        }

        for (int k0 = 0; k0 < K; k0 += 32) {
            const int cur = (k0 >> 5) & 1;
            __syncthreads();                      // publish buf[cur]
            if (k0 + 32 < K) {                    // prefetch next into buf[cur^1]
                const int kn = k0 + 32;
                #pragma unroll
                for (int t = 0; t < CH / NW; ++t) {
                    int c = wid + t * NW;
                    if (c < CH_A) {
                        GLD16(Ause + (bm + c * 16 + r4) * (long)lda + kn + c4 * 8,
                              &As[cur ^ 1][c * 512 + lane * 8]);
                    } else {
                        int cb = c - CH_A;
                        GLD16(B + (bn + cb * 16 + r4) * (long)ldb + kn + c4 * 8,
                              &Bs[cur ^ 1][cb * 512 + lane * 8]);
                    }
                }
            }
            bhalf8 af[NI], bfr[NJ];
            #pragma unroll
            for (int i = 0; i < NI; ++i)
                af[i] = *(const bhalf8*)&As[cur][(wrow * WM + i * 16 + l15) * 32 + l4 * 8];
            #pragma unroll
            for (int j = 0; j < NJ; ++j)
                bfr[j] = *(const bhalf8*)&Bs[cur][(wcol * WN + j * 16 + l15) * 32 + l4 * 8];
            #pragma unroll
            for (int i = 0; i < NI; ++i)
                #pragma unroll
                for (int j = 0; j < NJ; ++j)
                    acc[i][j] = __builtin_amdgcn_mfma_f32_16x16x32_bf16(af[i], bfr[j], acc[i][j], 0, 0, 0);
        }

        if (VTT && vtp != nullptr && bn >= vc0) {
            // transposed epilogue through LDS (NW=1: BM=32, BN=64, 64 thr)
            #pragma unroll
            for (int j = 0; j < NJ; ++j) {
                const int cc = wcol * WN + j * 16 + l15;
                const float bv = bias ? bias[bn + cc] : 0.f;
                #pragma unroll
                for (int i = 0; i < NI; ++i) {
                    const int rw = wrow * WM + i * 16 + (l4 << 2);
                    #pragma unroll
                    for (int r = 0; r < 4; ++r)
                        TT[cc * TSTR + rw + r] = f2b(acc[i][j][r] + bv);
                }
            }
            __syncthreads();
            {
                const int cc = tid;                // 64 threads = 64 cols
                const u16* src = &TT[cc * TSTR];
                u16* dst = &vtp[(bn - vc0 + cc) * 2048 + bm];
                #pragma unroll
                for (int p = 0; p < BM / 8; ++p)
                    *(uint4*)(dst + p * 8) = *(const uint4*)(src + p * 8);
            }
            __syncthreads();
            continue;
        }

        float* Cf = (float*)Cv + blockIdx.z * zoffC;
        u16*   Cb = (u16*)Cv  + blockIdx.z * zoffC;
        const int rowb = wrow * WM + (l4 << 2);
        const int colb = wcol * WN + l15;
        #pragma unroll
        for (int j = 0; j < NJ; ++j) {
            const long gc = bn + colb + j * 16;
            const float bv = bias ? bias[gc] : 0.f;
            #pragma unroll
            for (int i = 0; i < NI; ++i) {
                const long gr = bm + rowb + i * 16;
                #pragma unroll
                for (int r = 0; r < 4; ++r) {
                    float v = acc[i][j][r] + bv;
                    if (RELU) v = fmaxf(v, 0.f);
                    if (OUT == 0) {
                        if (NT) __builtin_nontemporal_store(v, &Cf[(gr + r) * (long)ldc + gc]);
                        else    Cf[(gr + r) * (long)ldc + gc] = v;
                    } else {
                        Cb[(gr + r) * (long)ldc + gc] = f2b(v);
                    }
                }
            }
        }
    }
}

// ---------------------------------------------------------------------------
// Fused GEMM + residual + LayerNorm (N=512 full row per block). K=512.
// grid = M/16 blocks, 512 threads = 8 waves; wave w owns cols w*64..w*64+63.
// ---------------------------------------------------------------------------
__global__ __launch_bounds__(512)
void gemm_ln_kernel(const u16* __restrict__ A, const u16* __restrict__ B,
                    const float* __restrict__ bias,
                    float* __restrict__ x, u16* __restrict__ xb,
                    const float* __restrict__ g, const float* __restrict__ bb,
                    int K)
{
    __shared__ u16 As[16 * 32];
    __shared__ u16 Bs[512 * 32];
    __shared__ float red[2][16][8];
    __shared__ float mv[2][16];

    const int tid = threadIdx.x, w = tid >> 6, lane = tid & 63;
    const int l15 = lane & 15, l4 = lane >> 4;
    const int r4 = lane >> 2, c4 = lane & 3;
    const long bm = (long)blockIdx.x * 16;

    f32x4 acc[4];
    #pragma unroll
    for (int j = 0; j < 4; ++j) acc[j] = (f32x4){0.f, 0.f, 0.f, 0.f};

    for (int k0 = 0; k0 < K; k0 += 32) {
        #pragma unroll
        for (int t = 0; t < 5; ++t) {
            int c = w + t * 8;
            if (c < 33) {
                if (c == 0) {
                    GLD16(A + (bm + r4) * (long)K + k0 + c4 * 8, As + lane * 8);
                } else {
                    GLD16(B + ((c - 1) * 16 + r4) * (long)K + k0 + c4 * 8,
                          Bs + (c - 1) * 512 + lane * 8);
                }
            }
        }
        __syncthreads();
        bhalf8 af = *(const bhalf8*)&As[l15 * 32 + l4 * 8];
        #pragma unroll
        for (int j = 0; j < 4; ++j) {
            bhalf8 bf = *(const bhalf8*)&Bs[(w * 64 + j * 16 + l15) * 32 + l4 * 8];
            acc[j] = __builtin_amdgcn_mfma_f32_16x16x32_bf16(af, bf, acc[j], 0, 0, 0);
        }
        __syncthreads();
    }

    // epilogue: residual + row stats + LN
    float vbuf[4][4], s[4] = {0, 0, 0, 0}, s2[4] = {0, 0, 0, 0};
    #pragma unroll
    for (int j = 0; j < 4; ++j) {
        int col = w * 64 + j * 16 + l15;
        float bv = bias[col];
        #pragma unroll
        for (int r = 0; r < 4; ++r) {
            int row = l4 * 4 + r;
            float v = acc[j][r] + bv + x[(bm + row) * 512 + col];
            vbuf[j][r] = v;
            s[r] += v; s2[r] += v * v;
        }
    }
    #pragma unroll
    for (int r = 0; r < 4; ++r) { s[r] = redsum16(s[r]); s2[r] = redsum16(s2[r]); }
    if (l15 == 0) {
        #pragma unroll
        for (int r = 0; r < 4; ++r) {
            red[0][l4 * 4 + r][w] = s[r];
            red[1][l4 * 4 + r][w] = s2[r];
        }
    }
    __syncthreads();
    if (tid < 16) {
        float S = 0.f, S2 = 0.f;
        #pragma unroll
        for (int q = 0; q < 8; ++q) { S += red[0][tid][q]; S2 += red[1][tid][q]; }
        float mean = S * (1.f / 512.f);
        float var = S2 * (1.f / 512.f) - mean * mean;
        mv[0][tid] = mean;
        mv[1][tid] = rsqrtf(var + 1e-6f);
    }
    __syncthreads();
    #pragma unroll
    for (int j = 0; j < 4; ++j) {
        int col = w * 64 + j * 16 + l15;
        float gg = g[col], bbv = bb[col];
        #pragma unroll
        for (int r = 0; r < 4; ++r) {
            int row = l4 * 4 + r;
            float o = (vbuf[j][r] - mv[0][row]) * mv[1][row] * gg + bbv;
            x[(bm + row) * 512 + col] = o;
            xb[(bm + row) * 512 + col] = f2b(o);
        }
    }
}

// ---------------------------------------------------------------------------
// Fused flash attention. One (b,h,64-q-block) per workgroup, 4 waves x 16 q.
// K/V tiles double-buffered; one barrier per tile. s_setprio around MFMA (T5).
// ---------------------------------------------------------------------------
template<int CAUSAL>
__global__ __launch_bounds__(256)
void flash_kernel(const u16* __restrict__ Qp, int ldq,
                  const u16* __restrict__ Kp, int ldk,
                  const u16* __restrict__ Vt,
                  const int* __restrict__ tok,
                  u16* __restrict__ Op)
{
    __shared__ u16 QS[64 * 64];
    __shared__ u16 KS[2][64 * 64];
    __shared__ u16 VS[2][64 * 64];
    __shared__ u16 PS[4 * 16 * 64];
    __shared__ float MK[512];

    const int tid = threadIdx.x, lane = tid & 63, w = tid >> 6;
    const int l15 = lane & 15, l4 = lane >> 4;
    const int qb = blockIdx.x, bh = blockIdx.y;
    const int b = bh >> 3, h = bh & 7;

    const u16* Q = Qp + (long)(b * 512 + qb * 64) * ldq + h * 64;
    const u16* K = Kp + (long)(b * 512) * ldk + h * 64;
    const u16* V = Vt + (long)(h * 64) * 2048 + b * 512;
    u16* O = Op + (long)(b * 512 + qb * 64) * 512 + h * 64;

    {
        int t0 = tok[b * 512 + tid];
        int t1 = tok[b * 512 + 256 + tid];
        MK[tid]       = (t0 == 0) ? -1e9f : 0.f;
        MK[tid + 256] = (t1 == 0) ? -1e9f : 0.f;
    }
    const int r = tid >> 3;
    const int c = (tid & 7) ^ (r & 7);
    {
        GLD16(Q + (long)r * ldq + c * 8,        QS + tid * 8);
        GLD16(Q + (long)(r + 32) * ldq + c * 8, QS + 2048 + tid * 8);
        GLD16(K + (long)r * ldk + c * 8,              KS[0] + tid * 8);
        GLD16(K + (long)(32 + r) * ldk + c * 8,       KS[0] + 2048 + tid * 8);
        GLD16(V + (long)r * 2048 + c * 8,             VS[0] + tid * 8);
        GLD16(V + (long)(r + 32) * 2048 + c * 8,      VS[0] + 2048 + tid * 8);
    }
    __syncthreads();

    bhalf8 qa[2];
    #pragma unroll
    for (int kc = 0; kc < 2; ++kc) {
        int row = w * 16 + l15;
        qa[kc] = *(const bhalf8*)&QS[row * 64 + (((kc * 4 + l4) ^ (row & 7)) << 3)];
    }

    f32x4 oacc[4];
    float mrun[4], lrun[4];
    #pragma unroll
    for (int j = 0; j < 4; ++j) oacc[j] = (f32x4){0.f, 0.f, 0.f, 0.f};
    #pragma unroll
    for (int rr = 0; rr < 4; ++rr) { mrun[rr] = -1e30f; lrun[rr] = 0.f; }

    const int tmax = CAUSAL ? qb : 7;

    for (int t = 0; t <= tmax; ++t) {
        const int cur = t & 1;
        if (t < tmax) {
            const int tn = t + 1;
            GLD16(K + (long)(tn * 64 + r) * ldk + c * 8,        KS[cur ^ 1] + tid * 8);
            GLD16(K + (long)(tn * 64 + 32 + r) * ldk + c * 8,   KS[cur ^ 1] + 2048 + tid * 8);
            GLD16(V + (long)r * 2048 + tn * 64 + c * 8,         VS[cur ^ 1] + tid * 8);
            GLD16(V + (long)(r + 32) * 2048 + tn * 64 + c * 8,  VS[cur ^ 1] + 2048 + tid * 8);
        }
        f32x4 sac[4];
        #pragma unroll
        for (int jj = 0; jj < 4; ++jj) sac[jj] = (f32x4){0.f, 0.f, 0.f, 0.f};
        bhalf8 kf[4][2];
        #pragma unroll
        for (int jj = 0; jj < 4; ++jj)
            #pragma unroll
            for (int kc = 0; kc < 2; ++kc) {
                int row = jj * 16 + l15;
                kf[jj][kc] = *(const bhalf8*)&KS[cur][row * 64 + (((kc * 4 + l4) ^ (row & 7)) << 3)];
            }
        __builtin_amdgcn_s_setprio(1);
        #pragma unroll
        for (int jj = 0; jj < 4; ++jj)
            #pragma unroll
            for (int kc = 0; kc < 2; ++kc)
                sac[jj] = __builtin_amdgcn_mfma_f32_16x16x32_bf16(qa[kc], kf[jj][kc], sac[jj], 0, 0, 0);
        __builtin_amdgcn_s_setprio(0);

        #pragma unroll
        for (int jj = 0; jj < 4; ++jj) {
            float mk = MK[t * 64 + jj * 16 + l15];
            #pragma unroll
            for (int rr = 0; rr < 4; ++rr) {
                float mk2 = mk;
                if (CAUSAL && t == qb) {
                    int col = t * 64 + jj * 16 + l15;
                    int qr = qb * 64 + w * 16 + l4 * 4 + rr;
                    if (col > qr) mk2 = -1e9f;
                }
                sac[jj][rr] = sac[jj][rr] * 0.125f + mk2;
            }
        }
        #pragma unroll
        for (int rr = 0; rr < 4; ++rr) {
            float mx = fmaxf(fmaxf(sac[0][rr], sac[1][rr]), fmaxf(sac[2][rr], sac[3][rr]));
            mx = redmax16(mx);
            float mnew = fmaxf(mrun[rr], mx);
            float alpha = __expf(mrun[rr] - mnew);
            float sum = 0.f;
            int row_p = l4 * 4 + rr;
            #pragma unroll
            for (int jj = 0; jj < 4; ++jj) {
                float pv = __expf(sac[jj][rr] - mnew);
                sum += pv;
                int kv = jj * 16 + l15;
                PS[w * 1024 + row_p * 64 + ((((kv >> 3) ^ (row_p & 7)) << 3) | (kv & 7))] = f2b(pv);
            }
            sum = redsum16(sum);
            lrun[rr] = lrun[rr] * alpha + sum;
            mrun[rr] = mnew;
            #pragma unroll
            for (int jd = 0; jd < 4; ++jd) oacc[jd][rr] *= alpha;
        }
        bhalf8 pa[2], vf[4][2];
        #pragma unroll
        for (int kc = 0; kc < 2; ++kc) {
            int row = l15;
            pa[kc] = *(const bhalf8*)&PS[w * 1024 + row * 64 + (((kc * 4 + l4) ^ (row & 7)) << 3)];
        }
        #pragma unroll
        for (int jd = 0; jd < 4; ++jd)
            #pragma unroll
            for (int kc = 0; kc < 2; ++kc) {
                int row = jd * 16 + l15;
                vf[jd][kc] = *(const bhalf8*)&VS[cur][row * 64 + (((kc * 4 + l4) ^ (row & 7)) << 3)];
            }
        __builtin_amdgcn_s_setprio(1);
        #pragma unroll
        for (int jd = 0; jd < 4; ++jd)
            #pragma unroll
            for (int kc = 0; kc < 2; ++kc)
                oacc[jd] = __builtin_amdgcn_mfma_f32_16x16x32_bf16(pa[kc], vf[jd][kc], oacc[jd], 0, 0, 0);
        __builtin_amdgcn_s_setprio(0);
        __syncthreads();
    }

    #pragma unroll
    for (int rr = 0; rr < 4; ++rr) {
        float inv = 1.f / lrun[rr];
        int row = w * 16 + l4 * 4 + rr;
        #pragma unroll
        for (int jd = 0; jd < 4; ++jd)
            O[(long)row * 512 + jd * 16 + l15] = f2b(oacc[jd][rr] * inv);
    }
}

// ---------------------------------------------------------------------------
// Prep kernels (unchanged)
// ---------------------------------------------------------------------------
__global__ __launch_bounds__(256)
void transpose_many(const float* __restrict__ inA, const float* __restrict__ inB,
                    int zsplit, int R, int C, u16* __restrict__ out)
{
    int z = blockIdx.z;
    const float* in = (z < zsplit) ? inA + (long)z * R * C
                                   : inB + (long)(z - zsplit) * R * C;
    u16* o = out + (long)z * R * C;
    __shared__ float tb[64][65];
    const int tr = blockIdx.y * 64, tc = blockIdx.x * 64;
    const int col = threadIdx.x & 63, r0 = threadIdx.x >> 6;
    #pragma unroll
    for (int p = 0; p < 16; ++p) {
        int row = r0 * 16 + p;
        tb[row][col] = in[(long)(tr + row) * C + tc + col];
    }
    __syncthreads();
    #pragma unroll
    for (int p = 0; p < 16; ++p) {
        int row = r0 * 16 + p;
        o[(long)(tc + row) * R + tr + col] = f2b(tb[col][row]);
    }
}

__global__ __launch_bounds__(256)
void convert_b16(const float4* __restrict__ in, u16* __restrict__ out, long n4)
{
    long i = (long)blockIdx.x * 256 + threadIdx.x;
    if (i >= n4) return;
    float4 v = in[i];
    uint2 p;
    p.x = (unsigned)f2b(v.x) | ((unsigned)f2b(v.y) << 16);
    p.y = (unsigned)f2b(v.z) | ((unsigned)f2b(v.w) << 16);
    *(uint2*)(out + i * 4) = p;
}

// ---------------------------------------------------------------------------
// Embedding (both sequences in one dispatch): x = emb[tok]*scale + pos
// ---------------------------------------------------------------------------
__global__ __launch_bounds__(256)
void embed_kernel(const int* __restrict__ tE, const int* __restrict__ tD,
                  const float* __restrict__ eE, const float* __restrict__ eD,
                  const float* __restrict__ pos,
                  float* __restrict__ xE, float* __restrict__ xD,
                  u16* __restrict__ bE, u16* __restrict__ bD, float scale)
{
    const int z = blockIdx.y;
    const int* tok = z ? tD : tE;
    const float* emb = z ? eD : eE;
    float* x = z ? xD : xE;
    u16* xb = z ? bD : bE;
    int row = blockIdx.x;
    int s = row & (S_ - 1);
    int t = tok[row];
    const float* er = emb + (long)t * D_;
    const float* pr = pos + (long)s * D_;
    float* o = x + (long)row * D_;
    u16*  ob = xb + (long)row * D_;
    int i = threadIdx.x;
    float v0 = er[i]       * scale + pr[i];
    float v1 = er[i + 256] * scale + pr[i + 256];
    o[i] = v0;        o[i + 256] = v1;
    ob[i] = f2b(v0);  ob[i + 256] = f2b(v1);
}

// ---------------------------------------------------------------------------
// x = LayerNorm(x + y0 + y1 + cb) * g + b (fp32 state) + bf16 copy
// ---------------------------------------------------------------------------
__global__ __launch_bounds__(256)
void add_ln_kernel(float* __restrict__ x, const float* __restrict__ y0,
                   const float* __restrict__ y1, const float* __restrict__ cb,
                   u16* __restrict__ xb,
                   const float* __restrict__ g, const float* __restrict__ bb)
{
    long row = blockIdx.x;
    float* xr = x + row * D_;
    u16* xo = xb + row * D_;
    const float* yr0 = y0 + row * D_;
    const float* yr1 = y1 + row * D_;
    int t = threadIdx.x, t2 = t + 256;

    float r0 = xr[t]  + yr0[t]  + yr1[t]  + cb[t];
    float r1 = xr[t2] + yr0[t2] + yr1[t2] + cb[t2];
    float s = r0 + r1;
    float s2 = r0 * r0 + r1 * r1;
    #pragma unroll
    for (int i = 1; i < 64; i <<= 1) {
        s  += __shfl_xor(s, i);
        s2 += __shfl_xor(s2, i);
    }
    __shared__ float rs[4], rs2[4];
    int wid = t >> 6;
    if ((t & 63) == 0) { rs[wid] = s; rs2[wid] = s2; }
    __syncthreads();
    s  = rs[0] + rs[1] + rs[2] + rs[3];
    s2 = rs2[0] + rs2[1] + rs2[2] + rs2[3];

    float mean = s * (1.f / D_);
    float var  = s2 * (1.f / D_) - mean * mean;
    float inv  = rsqrtf(var + 1e-6f);
    float o0 = (r0 - mean) * inv * g[t]  + bb[t];
    float o1 = (r1 - mean) * inv * g[t2] + bb[t2];
    xr[t] = o0;       xr[t2] = o1;
    xo[t] = f2b(o0);  xo[t2] = f2b(o1);
}

// ---------------------------------------------------------------------------
extern "C" void kernel_launch(void* const* d_in, const int* in_sizes, int n_in,
                              void* d_out, int out_size, void* d_ws, size_t ws_size,
                              hipStream_t stream)
{
    const int*   enc_in     = (const int*)  d_in[0];
    const int*   dec_in     = (const int*)  d_in[1];
    const float* e_embed    = (const float*)d_in[2];
    const float* d_embed    = (const float*)d_in[3];
    const float* pos_enc    = (const float*)d_in[4];
    const float* enc_mha_W  = (const float*)d_in[5];
    const float* enc_mha_b  = (const float*)d_in[6];
    const float* enc_ln_g   = (const float*)d_in[7];
    const float* enc_ln_b   = (const float*)d_in[8];
    const float* enc_ffn_W1 = (const float*)d_in[9];
    const float* enc_ffn_b1 = (const float*)d_in[10];
    const float* enc_ffn_W2 = (const float*)d_in[11];
    const float* enc_ffn_b2 = (const float*)d_in[12];
    const float* dec_mha_W  = (const float*)d_in[13];
    const float* dec_mha_b  = (const float*)d_in[14];
    const float* dec_ln_g   = (const float*)d_in[15];
    const float* dec_ln_b   = (const float*)d_in[16];
    const float* dec_ffn_W1 = (const float*)d_in[17];
    const float* dec_ffn_b1 = (const float*)d_in[18];
    const float* dec_ffn_W2 = (const float*)d_in[19];
    const float* dec_ffn_b2 = (const float*)d_in[20];
    float* out = (float*)d_out;

    const int  BS  = B_ * S_;                 // 2048
    const long BSD = (long)BS * D_;
    const long DD  = (long)D_ * D_;
    const long DF  = (long)D_ * F_;

    char* p = (char*)d_ws;
    auto alloc = [&](long bytes) { char* r = p; p += (bytes + 255) & ~255L; return r; };
    float* e    = (float*)alloc(BSD * 4);
    float* dd   = (float*)alloc(BSD * 4);
    float* y    = (float*)alloc(2 * BSD * 4);   // split-K partials y0,y1
    u16*   eb   = (u16*)  alloc(BSD * 2);
    u16*   ddb  = (u16*)  alloc(BSD * 2);
    u16*   qkv  = (u16*)  alloc((long)BS * 1536 * 2);
    u16*   att  = (u16*)  alloc(BSD * 2);
    u16*   vt   = (u16*)  alloc(BSD * 2);
    u16*   ffnh = (u16*)  alloc((long)BS * F_ * 2);
    u16*   wEmb = (u16*)  alloc((long)V_ * D_ * 2);
    u16*   wMha = (u16*)  alloc(72 * DD * 2);
    u16*   wF1  = (u16*)  alloc(12 * DF * 2);
    u16*   wF2  = (u16*)  alloc(12 * DF * 2);

    // ---- weight prep ----
    transpose_many<<<dim3(8, 8, 72), 256, 0, stream>>>(enc_mha_W, dec_mha_W, 24, 512, 512, wMha);
    transpose_many<<<dim3(32, 8, 12), 256, 0, stream>>>(enc_ffn_W1, dec_ffn_W1, 6, 512, 2048, wF1);
    transpose_many<<<dim3(8, 32, 12), 256, 0, stream>>>(enc_ffn_W2, dec_ffn_W2, 6, 2048, 512, wF2);
    convert_b16<<<16000, 256, 0, stream>>>((const float4*)d_embed, wEmb, (long)V_ * D_ / 4);

    const float scale = sqrtf((float)D_);
    embed_kernel<<<dim3(BS, 2), 256, 0, stream>>>(enc_in, dec_in, e_embed, d_embed,
                                                  pos_enc, e, dd, eb, ddb, scale);

    // 1-wave 32x64 skinny GEMM (+V-transpose epilogue), 1536 blocks, 6/CU
    #define GEMM_SKV(A, Bp, bias, C) \
        mfma_gemm<1,1,32,64,1,0,1,0,0,1,0><<<dim3(24, 64), 64, 0, stream>>>( \
            A, A, 1 << 30, Bp, bias, C, 512, 512, 512, 1536, vt, 1024, 0)
    // FFN1: 1-wave 32x64 skinny, 2048 blocks, 8/CU
    #define GEMM_FFN1(A, Bp, bias, C) \
        mfma_gemm<1,1,32,64,1,1,1,0,0,0,0><<<dim3(32, 64), 64, 0, stream>>>( \
            A, A, 1 << 30, Bp, bias, C, 512, 512, 512, 2048, nullptr, 0, 0)
    // FFN2: split-K=2, 1-wave 32x64 independent blocks, 1024 blocks
    #define GEMM_FFN2(A, Bp) \
        mfma_gemm<1,1,32,64,0,0,1,0,0,0,0><<<dim3(8, 64, 2), 64, 0, stream>>>( \
            A, A, 1 << 30, Bp, nullptr, y, 1024, 2048, 2048, 512, nullptr, 0, BSD)

    // ---------------- encoder ----------------
    for (int l = 0; l < L_; ++l) {
        const u16* Wl = wMha + (long)l * 4 * DD;
        const float* bl = enc_mha_b + (long)l * 4 * D_;
        GEMM_SKV(eb, Wl, bl, qkv);
        flash_kernel<0><<<dim3(8, 32), 256, 0, stream>>>(qkv, 1536, qkv + 512, 1536, vt, enc_in, att);
        gemm_ln_kernel<<<128, 512, 0, stream>>>(att, Wl + 3 * DD, bl + 3 * D_,
            e, eb, enc_ln_g + (long)(l * 2) * D_, enc_ln_b + (long)(l * 2) * D_, 512);
        GEMM_FFN1(eb, wF1 + (long)l * DF, enc_ffn_b1 + (long)l * F_, ffnh);
        GEMM_FFN2(ffnh, wF2 + (long)l * DF);
        add_ln_kernel<<<BS, 256, 0, stream>>>(e, y, y + BSD, enc_ffn_b2 + (long)l * D_, eb,
            enc_ln_g + (long)(l * 2 + 1) * D_, enc_ln_b + (long)(l * 2 + 1) * D_);
    }

    // ---------------- decoder ----------------
    for (int l = 0; l < L_; ++l) {
        const u16* Wl = wMha + (long)(24 + l * 8) * DD;
        const float* bl = dec_mha_b + (long)l * 8 * D_;
        // self-attention (causal + dec pad)
        GEMM_SKV(ddb, Wl, bl, qkv);
        flash_kernel<1><<<dim3(8, 32), 256, 0, stream>>>(qkv, 1536, qkv + 512, 1536, vt, dec_in, att);
        gemm_ln_kernel<<<128, 512, 0, stream>>>(att, Wl + 3 * DD, bl + 3 * D_,
            dd, ddb, dec_ln_g + (long)(l * 3) * D_, dec_ln_b + (long)(l * 3) * D_, 512);
        // cross-attention: fused q (from dd) + k,v (from e) projections
        mfma_gemm<1,1,32,64,1,0,1,1,0,1,0><<<dim3(24, 64), 64, 0, stream>>>(
            ddb, eb, 512, Wl + 4 * DD, bl + 4 * D_, qkv,
            512, 512, 512, 1536, vt, 1024, 0);
        flash_kernel<0><<<dim3(8, 32), 256, 0, stream>>>(qkv, 1536, qkv + 512, 1536, vt, enc_in, att);
        gemm_ln_kernel<<<128, 512, 0, stream>>>(att, Wl + 7 * DD, bl + 7 * D_,
            dd, ddb, dec_ln_g + (long)(l * 3 + 1) * D_, dec_ln_b + (long)(l * 3 + 1) * D_, 512);
        // FFN
        GEMM_FFN1(ddb, wF1 + (long)(6 + l) * DF, dec_ffn_b1 + (long)l * F_, ffnh);
        GEMM_FFN2(ffnh, wF2 + (long)(6 + l) * DF);
        add_ln_kernel<<<BS, 256, 0, stream>>>(dd, y, y + BSD, dec_ffn_b2 + (long)l * D_, ddb,
            dec_ln_g + (long)(l * 3 + 2) * D_, dec_ln_b + (long)(l * 3 + 2) * D_);
    }

    // ---------------- logits = dd @ d_embed^T ----------------
    // XCD-swizzled 1D grid, 128x256 tile (2x4 waves), MLOOP=2
    mfma_gemm<2,4,64,64,0,0,2,0,1,0,1><<<dim3(1000), 512, 0, stream>>>(
        ddb, ddb, 1 << 30, wEmb, nullptr, out, 512, 512, 512, 32000, nullptr, 0, 0);
}